// Round 5
// baseline (502.968 us; speedup 1.0000x reference)
//
#include <hip/hip_runtime.h>
#include <hip/hip_bf16.h>

// EfficientLinearAttention on MI355X (gfx950).
// B=8 T=8192 C=512 H=8 D=64.  M = B*T = 65536 rows.
// External tensors fp32, internal compute bf16, output fp32.
//
// Pipeline:
//   cvt_x    : x fp32 -> bf16 xb            (in d_out[0:64MiB))
//   cvt_wb   : Wq/Wk/Wv/Wo + biases -> bf16 Wpack/bpack (ws)
//   qkv_gemm : fused Q/K/V projection, 256x256 tile deep pipeline
//   kv_reduce: per-(bh,chunk) partial KV = K^T V + Ksum partial, NO atomics
//   kv_pack  : fold 16 chunk-partials, write Ks + bf16 KVb fragments
//   attn_apply: attn = (Q@KV)/(Q.Ksum+1e-6), in-place on ws.Qb
//   out_gemm : out = attn@Wo^T+bo -> d_out fp32
//
// R7 changes vs R6 (494 us; qkv 162 us = 607 TF, structure-bound):
//   * gemm256_core: 256x256 tile, 8 waves (2Mx4N), 512 thr, BK=32,
//     4-deep LDS ring (128 KiB).  Buffer t&3 holds K-tile t; staging t+2
//     writes buffer (t+2)&3 which held tile t-2 (dead) -> race-free by
//     construction.  2 phases/K-tile, each {ds_read frags; issue 2
//     global_load_lds; barrier; lgkmcnt(0); setprio(1); 16 MFMA;
//     setprio(0); barrier}; vmcnt(4) once per K-tile (t+2's loads stay in
//     flight across barriers; vmcnt(0) only at t=14).  This is the
//     fine-interleave + counted-vmcnt combo (T3+T4+T5).
//   * XOR swizzle source-and-read (slot ^= row&3): frag ds_read_b128
//     16-way -> 4-way.
//   * Epilogues: LDS-restage passes -> uint4/float4 stores.
//   * kv_reduce/kv_pack/attn_apply/cvt unchanged (R6-verified).

typedef unsigned short u16t;
typedef unsigned int   u32t;
typedef __bf16 v8bf __attribute__((ext_vector_type(8)));
typedef u16t   v8u  __attribute__((ext_vector_type(8)));
typedef float  v4f  __attribute__((ext_vector_type(4)));

static __device__ __forceinline__ float bf2f(u16t b) {
    u32t u = ((u32t)b) << 16;
    return __builtin_bit_cast(float, u);
}
static __device__ __forceinline__ u16t f2bf(float f) {
    u32t u = __builtin_bit_cast(u32t, f);
    u += 0x7fffu + ((u >> 16) & 1u);   // round-to-nearest-even
    return (u16t)(u >> 16);
}
static __device__ __forceinline__ v8u cvt8(const float* p) {
    const float4 a = *(const float4*)p;
    const float4 b = *(const float4*)(p + 4);
    v8u r;
    r[0] = f2bf(a.x); r[1] = f2bf(a.y); r[2] = f2bf(a.z); r[3] = f2bf(a.w);
    r[4] = f2bf(b.x); r[5] = f2bf(b.y); r[6] = f2bf(b.z); r[7] = f2bf(b.w);
    return r;
}

// async global->LDS, 16B per lane; LDS dest must be base+lane*16 contiguous.
#define GLDS16(g, l) __builtin_amdgcn_global_load_lds(                       \
        (const __attribute__((address_space(1))) void*)(g),                  \
        (__attribute__((address_space(3))) void*)(l), 16, 0, 0)

// counted vmcnt wait (volatile asm = hard scheduling boundary for VMEM)
#define WAITV(N) asm volatile("s_waitcnt vmcnt(" #N ")" ::: "memory")
// raw barrier without the __syncthreads vmcnt(0) drain
#define BARRIER() do { __builtin_amdgcn_sched_barrier(0);                    \
                       __builtin_amdgcn_s_barrier();                         \
                       __builtin_amdgcn_sched_barrier(0); } while (0)
// lgkm drain + hard fence so MFMA can't hoist above it (rule #18)
#define LGKM0() do { asm volatile("s_waitcnt lgkmcnt(0)" ::: "memory");      \
                     __builtin_amdgcn_sched_barrier(0); } while (0)

// ---------------------------------------------------------------------------
__global__ __launch_bounds__(256) void cvt_x(
        const float* __restrict__ src, u16t* __restrict__ dst) {
    const int i = (blockIdx.x * 256 + threadIdx.x) * 8;   // 16384 blocks
    *(v8u*)&dst[i] = cvt8(&src[i]);
}

__global__ __launch_bounds__(256) void cvt_wb(
        const float* __restrict__ Wq, const float* __restrict__ Wk,
        const float* __restrict__ Wv, const float* __restrict__ Wo,
        const float* __restrict__ bq, const float* __restrict__ bk,
        const float* __restrict__ bv, const float* __restrict__ bo,
        u16t* __restrict__ Wpack, u16t* __restrict__ bpack) {
    const int b = blockIdx.x;
    if (b < 512) {                       // 4 x 512x512 weights, 2048 elems/blk
        const int gidx = (b * 256 + threadIdx.x) * 8;     // [0, 1048576)
        const int seg = gidx >> 18;
        const int off = gidx & 262143;
        const float* src = (seg == 0) ? Wq : (seg == 1) ? Wk
                          : (seg == 2) ? Wv : Wo;
        *(v8u*)&Wpack[gidx] = cvt8(&src[off]);
    } else {                             // 4 biases of 512
        const int seg = b - 512;
        const float* src = (seg == 0) ? bq : (seg == 1) ? bk
                          : (seg == 2) ? bv : bo;
        if (threadIdx.x < 64) {
            const int off = threadIdx.x * 8;
            *(v8u*)&bpack[seg * 512 + off] = cvt8(&src[off]);
        }
    }
}

// ---------------------------------------------------------------------------
// 256x256 GEMM core: C_tile = A[256xK] @ W[256xK]^T, K=512 bf16, fp32 acc.
// 8 waves 2Mx4N; per-wave 128x64 out = acc[8][4] 16x16 frags.  BK=32.
//
// LDS ring: 4 buffers x 32KiB.  Per buffer (elems): A[2 mh][2 wrq][64][32]
// at +0 (8192), B[256][32] row-major at +8192.  Stage unit = 8KiB = 1
// global_load_lds per thread; A units = mh-halves, B units = row halves.
// K-slot swizzle: LDS[r][s] holds G[r][(s^(r&3))*8..]; read slot =
// quad^(l16&3) (r&3 == l16&3 for all fragment rows).
//
// Schedule per K-tile t (buffer t&3; stage buffer (t+2)&3 = tile t-2, dead):
//   ph1: ds_read A-lo frags (4xb128) + B frags (4xb128, kept in regs);
//        issue A-stage(t+2) (2 loads); BARRIER; LGKM0; 16 MFMA; BARRIER
//   ph2: ds_read A-hi frags; issue B-stage(t+2); BARRIER; LGKM0; 16 MFMA;
//        WAITV(4) [t<=13] / WAITV(0) [t==14]; BARRIER
// Gate proof: at end of tile t, <=4 loads outstanding = exactly t+2's
// -> tile t+1 (staged during t-1) fully resident before its reads.
// ---------------------------------------------------------------------------
static __device__ __forceinline__ void gemm256_core(
        const u16t* __restrict__ A, const u16t* __restrict__ W,
        size_t mbase, int nbase, u16t* sm, v4f acc[8][4], int tid) {
    const int lane = tid & 63, w = tid >> 6;
    const int quad = lane >> 4, l16 = lane & 15;
    const int wr = w >> 2, wc = w & 3;

#pragma unroll
    for (int i = 0; i < 8; ++i)
#pragma unroll
        for (int j = 0; j < 4; ++j) acc[i][j] = (v4f){0.f, 0.f, 0.f, 0.f};

    // stage source pointers (per thread), swizzled k-slot on the SOURCE
    const int rS   = (tid >> 2) & 63;        // A row-in-unit
    const int wrqS = tid >> 8;               // A wr-quarter
    const u16t* pa = A + (mbase + wrqS * 128 + rS) * 512
                       + ((tid & 3) ^ (rS & 3)) * 8;
    const int rB = tid >> 2;                 // B row-in-unit (0..127)
    const u16t* pb = W + (size_t)(nbase + rB) * 512
                       + ((tid & 3) ^ (rB & 3)) * 8;
    u16t* const dA = sm + tid * 8;           // + buf*16384 (+4096 for mh=1)
    u16t* const dB = sm + 8192 + tid * 8;    // + buf*16384 (+4096 for hi rows)

    const int sl8 = (quad ^ (l16 & 3)) * 8;  // un-swizzled read slot
    const int aRd = wr * 2048 + l16 * 32 + sl8;
    const int bRd = 8192 + (wc * 64 + l16) * 32 + sl8;

#define ST_A(sb, kt) do {                                                    \
        GLDS16(pa + (kt) * 32, dA + (sb) * 16384);                           \
        GLDS16(pa + 64 * 512 + (kt) * 32, dA + (sb) * 16384 + 4096);         \
    } while (0)
#define ST_B(sb, kt) do {                                                    \
        GLDS16(pb + (kt) * 32, dB + (sb) * 16384);                           \
        GLDS16(pb + 128 * 512 + (kt) * 32, dB + (sb) * 16384 + 4096);        \
    } while (0)

    // prologue: tiles 0,1 staged; wait tile 0 (4 loads), tile 1 in flight
    ST_A(0, 0); ST_B(0, 0); ST_A(1, 1); ST_B(1, 1);
    WAITV(4); BARRIER();

#pragma unroll
    for (int t = 0; t < 16; ++t) {
        const int buf = (t & 3) * 16384;
        const int sb  = (t + 2) & 3;
        v8bf af[4], bf[4];
        // -------- phase 1: quadrant mh=0 --------
#pragma unroll
        for (int j = 0; j < 4; ++j)
            af[j] = *(const v8bf*)&sm[buf + aRd + j * 512];
#pragma unroll
        for (int n = 0; n < 4; ++n)
            bf[n] = *(const v8bf*)&sm[buf + bRd + n * 512];
        if (t < 14) ST_A(sb, t + 2);
        BARRIER();
        LGKM0();
        __builtin_amdgcn_s_setprio(1);
#pragma unroll
        for (int j = 0; j < 4; ++j)
#pragma unroll
            for (int n = 0; n < 4; ++n)
                acc[j][n] = __builtin_amdgcn_mfma_f32_16x16x32_bf16(
                    af[j], bf[n], acc[j][n], 0, 0, 0);
        __builtin_amdgcn_s_setprio(0);
        BARRIER();
        // -------- phase 2: quadrant mh=1 (B frags reused from regs) ------
#pragma unroll
        for (int j = 0; j < 4; ++j)
            af[j] = *(const v8bf*)&sm[buf + 4096 + aRd + j * 512];
        if (t < 14) ST_B(sb, t + 2);
        BARRIER();
        LGKM0();
        __builtin_amdgcn_s_setprio(1);
#pragma unroll
        for (int j = 0; j < 4; ++j)
#pragma unroll
            for (int n = 0; n < 4; ++n)
                acc[4 + j][n] = __builtin_amdgcn_mfma_f32_16x16x32_bf16(
                    af[j], bf[n], acc[4 + j][n], 0, 0, 0);
        __builtin_amdgcn_s_setprio(0);
        if (t <= 13)      { WAITV(4); }
        else if (t == 14) { WAITV(0); }
        BARRIER();
    }
#undef ST_A
#undef ST_B
}

// Fused Q/K/V projection.  1536 blocks x 512 thr; XCD-bijective remap
// (1536 = 8*192); the 6 (p,nt)-blocks of one m-tile consecutive on one XCD.
__global__ __launch_bounds__(512, 2) void qkv_gemm(
        const u16t* __restrict__ xb, const u16t* __restrict__ Wpack,
        const u16t* __restrict__ bpack,
        u16t* __restrict__ Qb, u16t* __restrict__ Kb, u16t* __restrict__ Vb) {
    __shared__ __align__(16) u16t sm[65536];   // 128KiB ring / Cs[128][264]
    const u32t id = blockIdx.x;
    const u32t wg = (id & 7) * 192 + (id >> 3);
    const int sub = (int)(wg % 6u);
    const int p = sub >> 1;
    const int nbase = (sub & 1) * 256;
    const size_t mbase = (size_t)(wg / 6u) * 256;
    const u16t* Wt = Wpack + (size_t)p * 262144;
    const u16t* bias = bpack + p * 512;
    u16t* C = (p == 0) ? Qb : (p == 1) ? Kb : Vb;
    const bool elu = (p < 2);
    const int tid = threadIdx.x;
    const int w = tid >> 6, lane = tid & 63, quad = lane >> 4, l16 = lane & 15;
    const int wr = w >> 2, wc = w & 3;

    v4f acc[8][4];
    gemm256_core(xb, Wt, mbase, nbase, sm, acc, tid);
    __syncthreads();                     // ring fully consumed -> reuse

    // Epilogue: two 128-row passes via LDS -> uint4 stores.
    u16t (*Cs)[264] = (u16t(*)[264])sm;
#pragma unroll
    for (int pass = 0; pass < 2; ++pass) {
        if (wr == pass) {
#pragma unroll
            for (int ni = 0; ni < 4; ++ni) {
                const int lcol = wc * 64 + ni * 16 + l16;
                const float bb = bf2f(bias[nbase + lcol]);
#pragma unroll
                for (int mi = 0; mi < 8; ++mi)
#pragma unroll
                    for (int r = 0; r < 4; ++r) {
                        float v = acc[mi][ni][r] + bb;
                        if (elu) v = (v > 0.f) ? (v + 1.f) : __expf(v);
                        Cs[mi * 16 + quad * 4 + r][lcol] = f2bf(v);
                    }
            }
        }
        __syncthreads();
#pragma unroll
        for (int rd = 0; rd < 8; ++rd) {
            const int f = rd * 512 + tid;    // [0,4096): 128 rows x 32 slots
            const int row = f >> 5;
            const int sl = f & 31;
            *(uint4*)&C[(mbase + pass * 128 + row) * 512 + nbase + sl * 8] =
                *(const uint4*)&Cs[row][sl * 8];
        }
        __syncthreads();
    }
}

// out = attn @ Wo^T + bo, fp32 out.  512 blocks x 512 thr, XCD remap.
__global__ __launch_bounds__(512, 2) void out_gemm(
        const u16t* __restrict__ attn, const u16t* __restrict__ Wo,
        const u16t* __restrict__ bo, float* __restrict__ C) {
    __shared__ __align__(16) u16t sm[65536];   // 128KiB ring / Cf[64][264]
    const u32t id = blockIdx.x;
    const u32t wg = (id & 7) * 64 + (id >> 3);
    const int nbase = (int)(wg & 1u) * 256;
    const size_t mbase = (size_t)(wg >> 1) * 256;
    const int tid = threadIdx.x;
    const int w = tid >> 6, lane = tid & 63, quad = lane >> 4, l16 = lane & 15;
    const int wr = w >> 2, wc = w & 3;

    v4f acc[8][4];
    gemm256_core(attn, Wo, mbase, nbase, sm, acc, tid);
    __syncthreads();

    // fp32 tile: four 64-row passes via LDS -> float4 stores.
    float (*Cf)[264] = (float(*)[264])sm;
#pragma unroll
    for (int pass = 0; pass < 4; ++pass) {
        if (wr == (pass >> 1)) {
#pragma unroll
            for (int ni = 0; ni < 4; ++ni) {
                const int lcol = wc * 64 + ni * 16 + l16;
                const float bb = bf2f(bo[nbase + lcol]);
#pragma unroll
                for (int j = 0; j < 4; ++j) {
                    const int mi = (pass & 1) * 4 + j;
#pragma unroll
                    for (int r = 0; r < 4; ++r)
                        Cf[j * 16 + quad * 4 + r][lcol] = acc[mi][ni][r] + bb;
                }
            }
        }
        __syncthreads();
#pragma unroll
        for (int rd = 0; rd < 8; ++rd) {
            const int f = rd * 512 + tid;    // [0,4096): 64 rows x 64 f4slots
            const int row = f >> 6;
            const int sl = f & 63;
            *(float4*)&C[(mbase + pass * 64 + row) * 512 + nbase + sl * 4] =
                *(const float4*)&Cf[row][sl * 4];
        }
        __syncthreads();
    }
}

// ---------------------------------------------------------------------------
// Partial KV: Part[bh*16+chunk] = [65][64] fp32; rows 0..63 = K^T V over the
// chunk's 512 t-rows, row 64 = Ksum partial.  NO atomics.
// 1-D grid 1024 blocks, XCD-bijective remap: batch b -> XCD b, the 8
// h-blocks of one (b,chunk) adjacent in dispatch (row locality).
// ---------------------------------------------------------------------------
__global__ __launch_bounds__(256) void kv_reduce(
        const u16t* __restrict__ Kp, const u16t* __restrict__ Vp,
        float* __restrict__ Part) {
    __shared__ u16t Kl[64][66];
    __shared__ u16t Vl[64][66];
    const u32t id  = blockIdx.x;                   // [0,1024)
    const u32t swz = (id & 7) * 128 + (id >> 3);   // bijective
    const int h     = (int)(swz & 7);
    const int grp   = (int)(swz >> 3);             // b*16 + chunk
    const int b     = grp >> 4;
    const int chunk = grp & 15;
    const int bh    = b * 8 + h;
    const int tid = threadIdx.x;
    const int w = tid >> 6, lane = tid & 63, quad = lane >> 4, l16 = lane & 15;
    const int trow0 = tid >> 3;                    // 0..31
    const int c8 = (tid & 7) * 8;

    v4f acc[4];
#pragma unroll
    for (int i = 0; i < 4; ++i) acc[i] = (v4f){0.f, 0.f, 0.f, 0.f};
    float ks[8];
#pragma unroll
    for (int j = 0; j < 8; ++j) ks[j] = 0.f;

    size_t g0 = ((size_t)b * 8192 + chunk * 512 + trow0) * 512 + h * 64 + c8;
    size_t g1 = g0 + 32 * 512;
    uint4 kq0 = *(const uint4*)&Kp[g0];
    uint4 kq1 = *(const uint4*)&Kp[g1];
    uint4 vq0 = *(const uint4*)&Vp[g0];
    uint4 vq1 = *(const uint4*)&Vp[g1];

    for (int tile = 0; tile < 8; ++tile) {
        // stage current regs to LDS, fold Ksum
        *(u32t*)&Kl[trow0][c8 + 0] = kq0.x;
        *(u32t*)&Kl[trow0][c8 + 2] = kq0.y;
        *(u32t*)&Kl[trow0][c8 + 4] = kq0.z;
        *(u32t*)&Kl[trow0][c8 + 6] = kq0.w;
        *(u32t*)&Kl[trow0 + 32][c8 + 0] = kq1.x;
        *(u32t*)&Kl[trow0 + 32][c8 + 2] = kq1.y;
        *(u32t*)&Kl[trow0 + 32][c8 + 4] = kq1.z;
        *(u32t*)&Kl[trow0 + 32][c8 + 6] = kq1.w;
        *(u32t*)&Vl[trow0][c8 + 0] = vq0.x;
        *(u32t*)&Vl[trow0][c8 + 2] = vq0.y;
        *(u32t*)&Vl[trow0][c8 + 4] = vq0.z;
        *(u32t*)&Vl[trow0][c8 + 6] = vq0.w;
        *(u32t*)&Vl[trow0 + 32][c8 + 0] = vq1.x;
        *(u32t*)&Vl[trow0 + 32][c8 + 2] = vq1.y;
        *(u32t*)&Vl[trow0 + 32][c8 + 4] = vq1.z;
        *(u32t*)&Vl[trow0 + 32][c8 + 6] = vq1.w;
        {
            const v8u ku0 = __builtin_bit_cast(v8u, kq0);
            const v8u ku1 = __builtin_bit_cast(v8u, kq1);
#pragma unroll
            for (int j = 0; j < 8; ++j)
                ks[j] += bf2f(ku0[j]) + bf2f(ku1[j]);
        }
        __syncthreads();
        // issue next tile's loads now: the end-of-tile barrier's vmcnt
        // drain is then covered by the LDS-read + MFMA phase below.
        if (tile < 7) {
            g0 += 64 * 512; g1 += 64 * 512;
            kq0 = *(const uint4*)&Kp[g0];
            kq1 = *(const uint4*)&Kp[g1];
            vq0 = *(const uint4*)&Vp[g0];
            vq1 = *(const uint4*)&Vp[g1];
        }
#pragma unroll
        for (int ts = 0; ts < 2; ++ts) {
            v8u au;
#pragma unroll
            for (int j = 0; j < 8; ++j)
                au[j] = Kl[ts * 32 + quad * 8 + j][w * 16 + l16];
            const v8bf af = __builtin_bit_cast(v8bf, au);
#pragma unroll
            for (int et = 0; et < 4; ++et) {
                v8u bu;
#pragma unroll
                for (int j = 0; j < 8; ++j)
                    bu[j] = Vl[ts * 32 + quad * 8 + j][et * 16 + l16];
                acc[et] = __builtin_amdgcn_mfma_f32_16x16x32_bf16(
                    af, __builtin_bit_cast(v8bf, bu), acc[et], 0, 0, 0);
            }
        }
        __syncthreads();
    }

    // store partial KV tile (plain coalesced stores)
    const size_t pbase = (size_t)(bh * 16 + chunk) * 4160;   // 65*64
#pragma unroll
    for (int et = 0; et < 4; ++et)
#pragma unroll
        for (int r = 0; r < 4; ++r)
            Part[pbase + (size_t)(w * 16 + quad * 4 + r) * 64 + et * 16 + l16]
                = acc[et][r];

    // Ksum partial: LDS tree (reuse Kl as float [32][65], 8320B <= 8448B)
    float* kr = (float*)&Kl[0][0];
#pragma unroll
    for (int j = 0; j < 8; ++j) kr[trow0 * 65 + c8 + j] = ks[j];
    __syncthreads();
    if (tid < 64) {
        float s = 0.f;
#pragma unroll
        for (int g = 0; g < 32; ++g) s += kr[g * 65 + tid];
        Part[pbase + 4096 + tid] = s;
    }
}

// Fold 16 chunk-partials -> Ks fp32 + KVb bf16 in MFMA B-fragment order.
__global__ __launch_bounds__(256) void kv_pack(
        const float* __restrict__ Part, u16t* __restrict__ KVb,
        float* __restrict__ Ks) {
    __shared__ float kvs[64][64];
    const int bh = blockIdx.x;
    const int tid = threadIdx.x;
    const size_t base = (size_t)bh * 16 * 4160;
#pragma unroll
    for (int rr = 0; rr < 4; ++rr) {
        const int fi = rr * 256 + tid;       // 1024 float4s = 64x64
        const int d = fi >> 4;
        const int e4 = (fi & 15) * 4;
        float4 s = make_float4(0.f, 0.f, 0.f, 0.f);
        for (int c = 0; c < 16; ++c) {
            const float4 p =
                *(const float4*)&Part[base + (size_t)c * 4160 + d * 64 + e4];
            s.x += p.x; s.y += p.y; s.z += p.z; s.w += p.w;
        }
        *(float4*)&kvs[d][e4] = s;
    }
    if (tid < 64) {
        float s = 0.f;
        for (int c = 0; c < 16; ++c)
            s += Part[base + (size_t)c * 4160 + 4096 + tid];
        Ks[bh * 64 + tid] = s;
    }
    __syncthreads();
#pragma unroll
    for (int i = 0; i < 2; ++i) {
        const int c = tid + i * 256;
        const int ksi = c >> 8;
        const int nb = (c >> 6) & 3;
        const int L = c & 63;
        const int quad = L >> 4, l16 = L & 15;
        v8u pk;
#pragma unroll
        for (int j = 0; j < 8; ++j)
            pk[j] = f2bf(kvs[ksi * 32 + quad * 8 + j][nb * 16 + l16]);
        *(v8u*)&KVb[((size_t)bh * 512 + c) * 8] = pk;
    }
}

// attn = (Q @ KV) / (Q.Ksum + 1e-6), in-place over Q.  grid (512, 8).
__global__ __launch_bounds__(256) void attn_apply(
        u16t* __restrict__ Q, const u16t* __restrict__ KVb,
        const float* __restrict__ Ksum) {
    __shared__ u16t Qs[128][72];
    __shared__ float ksl[64];
    __shared__ float rden[128];
    const int bx = blockIdx.x;
    const int h = blockIdx.y;
    const int b = bx >> 6;
    const int bh = b * 8 + h;
    const int tid = threadIdx.x;
    const int w = tid >> 6, lane = tid & 63, quad = lane >> 4, l16 = lane & 15;
    const size_t row0 = (size_t)bx * 128;

#pragma unroll
    for (int i = 0; i < 4; ++i) {
        const int cid = tid + i * 256;
        const int r = cid >> 3;
        const int c8 = (cid & 7) * 8;
        *(uint4*)&Qs[r][c8] = *(const uint4*)&Q[(row0 + r) * 512 + h * 64 + c8];
    }
    if (tid < 64) ksl[tid] = Ksum[bh * 64 + tid];
    __syncthreads();

    if (tid < 128) {
        float a = 1e-6f;
#pragma unroll
        for (int d = 0; d < 64; ++d) a += bf2f(Qs[tid][d]) * ksl[d];
        rden[tid] = 1.0f / fmaxf(a, 1e-9f);
    }

    v8bf bfr[2][4];
#pragma unroll
    for (int ksi = 0; ksi < 2; ++ksi)
#pragma unroll
        for (int nb = 0; nb < 4; ++nb)
            bfr[ksi][nb] = *(const v8bf*)
                &KVb[((size_t)bh * 512 + ksi * 256 + nb * 64 + lane) * 8];
    __syncthreads();

    v4f acc[2][4];
#pragma unroll
    for (int i = 0; i < 2; ++i)
#pragma unroll
        for (int j = 0; j < 4; ++j) acc[i][j] = (v4f){0.f, 0.f, 0.f, 0.f};

#pragma unroll
    for (int ksi = 0; ksi < 2; ++ksi) {
        v8bf af[2];
#pragma unroll
        for (int mt = 0; mt < 2; ++mt)
            af[mt] = *(const v8bf*)&Qs[w * 32 + mt * 16 + l16][ksi * 32 + quad * 8];
#pragma unroll
        for (int mt = 0; mt < 2; ++mt)
#pragma unroll
            for (int nb = 0; nb < 4; ++nb)
                acc[mt][nb] = __builtin_amdgcn_mfma_f32_16x16x32_bf16(
                    af[mt], bfr[ksi][nb], acc[mt][nb], 0, 0, 0);
    }

    // restage scaled result through Qs -> coalesced uint4 stores
    __syncthreads();                     // all waves done reading Qs
#pragma unroll
    for (int mt = 0; mt < 2; ++mt)
#pragma unroll
        for (int nb = 0; nb < 4; ++nb)
#pragma unroll
            for (int r = 0; r < 4; ++r) {
                const int rl = w * 32 + mt * 16 + quad * 4 + r;
                const int e = nb * 16 + l16;
                Qs[rl][e] = f2bf(acc[mt][nb][r] * rden[rl]);
            }
    __syncthreads();
#pragma unroll
    for (int i = 0; i < 4; ++i) {
        const int f = i * 256 + tid;         // [0,1024): 128 rows x 8 slots
        const int row = f >> 3;
        const int c8 = (f & 7) * 8;
        *(uint4*)&Q[(row0 + row) * 512 + h * 64 + c8] =
            *(const uint4*)&Qs[row][c8];
    }
}

// ---------------------------------------------------------------------------
extern "C" void kernel_launch(void* const* d_in, const int* in_sizes, int n_in,
                              void* d_out, int out_size, void* d_ws, size_t ws_size,
                              hipStream_t stream) {
    (void)in_sizes; (void)n_in; (void)out_size; (void)ws_size;
    const float* x32  = (const float*)d_in[0];
    const float* Wq32 = (const float*)d_in[1];
    const float* bq32 = (const float*)d_in[2];
    const float* Wk32 = (const float*)d_in[3];
    const float* bk32 = (const float*)d_in[4];
    const float* Wv32 = (const float*)d_in[5];
    const float* bv32 = (const float*)d_in[6];
    const float* Wo32 = (const float*)d_in[7];
    const float* bo32 = (const float*)d_in[8];

    // d_out (128 MiB fp32) doubles as scratch: xb bf16 + Vb bf16.
    // After qkv_gemm, xb is dead; kv_reduce reuses its space for Part
    // (1024 x 65*64 fp32 = 17MB), read back by kv_pack before out_gemm.
    u16t* xb = (u16t*)d_out;
    u16t* Vb = (u16t*)d_out + (size_t)33554432;
    float* Part = (float*)d_out;

    char* ws = (char*)d_ws;
    const size_t SZ   = (size_t)65536 * 512 * sizeof(u16t);    // 64 MiB
    const size_t KSB  = (size_t)64 * 64 * 4;                   // 16 KiB
    const size_t KVbB = (size_t)64 * 512 * 16;                 // 512 KiB
    u16t*  Qb    = (u16t*)(ws);
    u16t*  Kb    = (u16t*)(ws + SZ);
    float* Ks    = (float*)(ws + 2 * SZ);
    u16t*  KVb   = (u16t*)(ws + 2 * SZ + KSB);
    u16t*  Wpack = (u16t*)(ws + 2 * SZ + KSB + KVbB);
    u16t*  bpack = Wpack + (size_t)4 * 262144;

    const dim3 blk(256);
    cvt_x <<<dim3(16384), blk, 0, stream>>>(x32, xb);
    cvt_wb<<<dim3(516),   blk, 0, stream>>>(Wq32, Wk32, Wv32, Wo32,
                                            bq32, bk32, bv32, bo32,
                                            Wpack, bpack);
    qkv_gemm  <<<dim3(1536), dim3(512), 0, stream>>>(xb, Wpack, bpack,
                                                     Qb, Kb, Vb);
    kv_reduce <<<dim3(1024),   blk, 0, stream>>>(Kb, Vb, Part);
    kv_pack   <<<dim3(64),     blk, 0, stream>>>(Part, KVb, Ks);
    attn_apply<<<dim3(512, 8), blk, 0, stream>>>(Qb, KVb, Ks);
    out_gemm  <<<dim3(512), dim3(512), 0, stream>>>(Qb, Wpack + 3 * 262144,
                                                    bpack + 3 * 512,
                                                    (float*)d_out);
}

// Round 6
// 495.977 us; speedup vs baseline: 1.0141x; 1.0141x over previous
//
#include <hip/hip_runtime.h>
#include <hip/hip_bf16.h>

// EfficientLinearAttention on MI355X (gfx950).
// B=8 T=8192 C=512 H=8 D=64.  M = B*T = 65536 rows.
// External tensors fp32, internal compute bf16, output fp32.
//
// Pipeline:
//   cvt_x    : x fp32 -> bf16 xb            (in d_out[0:64MiB))
//   cvt_wb   : Wq/Wk/Wv/Wo + biases -> bf16 Wpack/bpack (ws)
//   qkv_gemm : fused Q/K/V projection, 256x256 tile deep pipeline
//   kv_reduce: per-(bh,chunk) partial KV = K^T V + Ksum partial, NO atomics
//   kv_pack  : fold 16 chunk-partials, write Ks + bf16 KVb fragments
//   attn_apply: attn = (Q@KV)/(Q.Ksum+1e-6), in-place on ws.Qb
//   out_gemm : out = attn@Wo^T+bo -> d_out fp32
//
// R8 changes vs R7 (503 us; qkv 178 us, SQ_LDS_BANK_CONFLICT 9.4e6):
//   * SWIZZLE FIX ONLY.  R7 used slot ^= row&3; rows are 64B (bank period
//     2) so lanes 4 apart shared both bank-start and slot -> 4-way conflict
//     on every frag b128 read (A and B), LDS-pipe-bound.  Restore the
//     period-8 swizzle proven in R6: source col ^= (row>>1)&3, read slot
//     = quad ^ ((l16>>1)&3) -> 2-way (the b128 floor, free per m136).
//   * Everything else unchanged from R7: 4-deep LDS ring, counted
//     vmcnt(4), fine interleave, setprio, epilogues, kv path.

typedef unsigned short u16t;
typedef unsigned int   u32t;
typedef __bf16 v8bf __attribute__((ext_vector_type(8)));
typedef u16t   v8u  __attribute__((ext_vector_type(8)));
typedef float  v4f  __attribute__((ext_vector_type(4)));

static __device__ __forceinline__ float bf2f(u16t b) {
    u32t u = ((u32t)b) << 16;
    return __builtin_bit_cast(float, u);
}
static __device__ __forceinline__ u16t f2bf(float f) {
    u32t u = __builtin_bit_cast(u32t, f);
    u += 0x7fffu + ((u >> 16) & 1u);   // round-to-nearest-even
    return (u16t)(u >> 16);
}
static __device__ __forceinline__ v8u cvt8(const float* p) {
    const float4 a = *(const float4*)p;
    const float4 b = *(const float4*)(p + 4);
    v8u r;
    r[0] = f2bf(a.x); r[1] = f2bf(a.y); r[2] = f2bf(a.z); r[3] = f2bf(a.w);
    r[4] = f2bf(b.x); r[5] = f2bf(b.y); r[6] = f2bf(b.z); r[7] = f2bf(b.w);
    return r;
}

// async global->LDS, 16B per lane; LDS dest must be base+lane*16 contiguous.
#define GLDS16(g, l) __builtin_amdgcn_global_load_lds(                       \
        (const __attribute__((address_space(1))) void*)(g),                  \
        (__attribute__((address_space(3))) void*)(l), 16, 0, 0)

// counted vmcnt wait (volatile asm = hard scheduling boundary for VMEM)
#define WAITV(N) asm volatile("s_waitcnt vmcnt(" #N ")" ::: "memory")
// raw barrier without the __syncthreads vmcnt(0) drain
#define BARRIER() do { __builtin_amdgcn_sched_barrier(0);                    \
                       __builtin_amdgcn_s_barrier();                         \
                       __builtin_amdgcn_sched_barrier(0); } while (0)
// lgkm drain + hard fence so MFMA can't hoist above it (rule #18)
#define LGKM0() do { asm volatile("s_waitcnt lgkmcnt(0)" ::: "memory");      \
                     __builtin_amdgcn_sched_barrier(0); } while (0)

// ---------------------------------------------------------------------------
__global__ __launch_bounds__(256) void cvt_x(
        const float* __restrict__ src, u16t* __restrict__ dst) {
    const int i = (blockIdx.x * 256 + threadIdx.x) * 8;   // 16384 blocks
    *(v8u*)&dst[i] = cvt8(&src[i]);
}

__global__ __launch_bounds__(256) void cvt_wb(
        const float* __restrict__ Wq, const float* __restrict__ Wk,
        const float* __restrict__ Wv, const float* __restrict__ Wo,
        const float* __restrict__ bq, const float* __restrict__ bk,
        const float* __restrict__ bv, const float* __restrict__ bo,
        u16t* __restrict__ Wpack, u16t* __restrict__ bpack) {
    const int b = blockIdx.x;
    if (b < 512) {                       // 4 x 512x512 weights, 2048 elems/blk
        const int gidx = (b * 256 + threadIdx.x) * 8;     // [0, 1048576)
        const int seg = gidx >> 18;
        const int off = gidx & 262143;
        const float* src = (seg == 0) ? Wq : (seg == 1) ? Wk
                          : (seg == 2) ? Wv : Wo;
        *(v8u*)&Wpack[gidx] = cvt8(&src[off]);
    } else {                             // 4 biases of 512
        const int seg = b - 512;
        const float* src = (seg == 0) ? bq : (seg == 1) ? bk
                          : (seg == 2) ? bv : bo;
        if (threadIdx.x < 64) {
            const int off = threadIdx.x * 8;
            *(v8u*)&bpack[seg * 512 + off] = cvt8(&src[off]);
        }
    }
}

// ---------------------------------------------------------------------------
// 256x256 GEMM core: C_tile = A[256xK] @ W[256xK]^T, K=512 bf16, fp32 acc.
// 8 waves 2Mx4N; per-wave 128x64 out = acc[8][4] 16x16 frags.  BK=32.
//
// LDS ring: 4 buffers x 32KiB.  Per buffer (elems): A[2 mh][2 wrq][64][32]
// at +0 (8192), B[256][32] row-major at +8192.  Stage unit = 8KiB = 1
// global_load_lds per thread; A units = mh-halves, B units = row halves.
// K-slot swizzle (period 8, matched to the 64B-row bank period of 2):
// LDS[r][s] holds G[r][(s ^ ((r>>1)&3))*8..]; read slot = quad^((l16>>1)&3)
// ((r>>1)&3 == (l16>>1)&3 for all fragment rows r = base + 16j + l16).
//
// Schedule per K-tile t (buffer t&3; stage buffer (t+2)&3 = tile t-2, dead):
//   ph1: ds_read A-lo frags (4xb128) + B frags (4xb128, kept in regs);
//        issue A-stage(t+2) (2 loads); BARRIER; LGKM0; 16 MFMA; BARRIER
//   ph2: ds_read A-hi frags; issue B-stage(t+2); BARRIER; LGKM0; 16 MFMA;
//        WAITV(4) [t<=13] / WAITV(0) [t==14]; BARRIER
// Gate proof: at end of tile t, <=4 loads outstanding = exactly t+2's
// -> tile t+1 (staged during t-1) fully resident before its reads.
// ---------------------------------------------------------------------------
static __device__ __forceinline__ void gemm256_core(
        const u16t* __restrict__ A, const u16t* __restrict__ W,
        size_t mbase, int nbase, u16t* sm, v4f acc[8][4], int tid) {
    const int lane = tid & 63, w = tid >> 6;
    const int quad = lane >> 4, l16 = lane & 15;
    const int wr = w >> 2, wc = w & 3;

#pragma unroll
    for (int i = 0; i < 8; ++i)
#pragma unroll
        for (int j = 0; j < 4; ++j) acc[i][j] = (v4f){0.f, 0.f, 0.f, 0.f};

    // stage source pointers (per thread), swizzled k-slot on the SOURCE
    const int rS   = (tid >> 2) & 63;        // A row-in-unit
    const int wrqS = tid >> 8;               // A wr-quarter
    const u16t* pa = A + (mbase + wrqS * 128 + rS) * 512
                       + ((tid & 3) ^ ((rS >> 1) & 3)) * 8;
    const int rB = tid >> 2;                 // B row-in-unit (0..127)
    const u16t* pb = W + (size_t)(nbase + rB) * 512
                       + ((tid & 3) ^ ((rB >> 1) & 3)) * 8;
    u16t* const dA = sm + tid * 8;           // + buf*16384 (+4096 for mh=1)
    u16t* const dB = sm + 8192 + tid * 8;    // + buf*16384 (+4096 for hi rows)

    const int sl8 = (quad ^ ((l16 >> 1) & 3)) * 8;  // un-swizzled read slot
    const int aRd = wr * 2048 + l16 * 32 + sl8;
    const int bRd = 8192 + (wc * 64 + l16) * 32 + sl8;

#define ST_A(sb, kt) do {                                                    \
        GLDS16(pa + (kt) * 32, dA + (sb) * 16384);                           \
        GLDS16(pa + 64 * 512 + (kt) * 32, dA + (sb) * 16384 + 4096);         \
    } while (0)
#define ST_B(sb, kt) do {                                                    \
        GLDS16(pb + (kt) * 32, dB + (sb) * 16384);                           \
        GLDS16(pb + 128 * 512 + (kt) * 32, dB + (sb) * 16384 + 4096);        \
    } while (0)

    // prologue: tiles 0,1 staged; wait tile 0 (4 loads), tile 1 in flight
    ST_A(0, 0); ST_B(0, 0); ST_A(1, 1); ST_B(1, 1);
    WAITV(4); BARRIER();

#pragma unroll
    for (int t = 0; t < 16; ++t) {
        const int buf = (t & 3) * 16384;
        const int sb  = (t + 2) & 3;
        v8bf af[4], bf[4];
        // -------- phase 1: quadrant mh=0 --------
#pragma unroll
        for (int j = 0; j < 4; ++j)
            af[j] = *(const v8bf*)&sm[buf + aRd + j * 512];
#pragma unroll
        for (int n = 0; n < 4; ++n)
            bf[n] = *(const v8bf*)&sm[buf + bRd + n * 512];
        if (t < 14) ST_A(sb, t + 2);
        BARRIER();
        LGKM0();
        __builtin_amdgcn_s_setprio(1);
#pragma unroll
        for (int j = 0; j < 4; ++j)
#pragma unroll
            for (int n = 0; n < 4; ++n)
                acc[j][n] = __builtin_amdgcn_mfma_f32_16x16x32_bf16(
                    af[j], bf[n], acc[j][n], 0, 0, 0);
        __builtin_amdgcn_s_setprio(0);
        BARRIER();
        // -------- phase 2: quadrant mh=1 (B frags reused from regs) ------
#pragma unroll
        for (int j = 0; j < 4; ++j)
            af[j] = *(const v8bf*)&sm[buf + 4096 + aRd + j * 512];
        if (t < 14) ST_B(sb, t + 2);
        BARRIER();
        LGKM0();
        __builtin_amdgcn_s_setprio(1);
#pragma unroll
        for (int j = 0; j < 4; ++j)
#pragma unroll
            for (int n = 0; n < 4; ++n)
                acc[4 + j][n] = __builtin_amdgcn_mfma_f32_16x16x32_bf16(
                    af[j], bf[n], acc[4 + j][n], 0, 0, 0);
        __builtin_amdgcn_s_setprio(0);
        if (t <= 13)      { WAITV(4); }
        else if (t == 14) { WAITV(0); }
        BARRIER();
    }
#undef ST_A
#undef ST_B
}

// Fused Q/K/V projection.  1536 blocks x 512 thr; XCD-bijective remap
// (1536 = 8*192); the 6 (p,nt)-blocks of one m-tile consecutive on one XCD.
__global__ __launch_bounds__(512, 2) void qkv_gemm(
        const u16t* __restrict__ xb, const u16t* __restrict__ Wpack,
        const u16t* __restrict__ bpack,
        u16t* __restrict__ Qb, u16t* __restrict__ Kb, u16t* __restrict__ Vb) {
    __shared__ __align__(16) u16t sm[65536];   // 128KiB ring / Cs[128][264]
    const u32t id = blockIdx.x;
    const u32t wg = (id & 7) * 192 + (id >> 3);
    const int sub = (int)(wg % 6u);
    const int p = sub >> 1;
    const int nbase = (sub & 1) * 256;
    const size_t mbase = (size_t)(wg / 6u) * 256;
    const u16t* Wt = Wpack + (size_t)p * 262144;
    const u16t* bias = bpack + p * 512;
    u16t* C = (p == 0) ? Qb : (p == 1) ? Kb : Vb;
    const bool elu = (p < 2);
    const int tid = threadIdx.x;
    const int w = tid >> 6, lane = tid & 63, quad = lane >> 4, l16 = lane & 15;
    const int wr = w >> 2, wc = w & 3;

    v4f acc[8][4];
    gemm256_core(xb, Wt, mbase, nbase, sm, acc, tid);
    __syncthreads();                     // ring fully consumed -> reuse

    // Epilogue: two 128-row passes via LDS -> uint4 stores.
    u16t (*Cs)[264] = (u16t(*)[264])sm;
#pragma unroll
    for (int pass = 0; pass < 2; ++pass) {
        if (wr == pass) {
#pragma unroll
            for (int ni = 0; ni < 4; ++ni) {
                const int lcol = wc * 64 + ni * 16 + l16;
                const float bb = bf2f(bias[nbase + lcol]);
#pragma unroll
                for (int mi = 0; mi < 8; ++mi)
#pragma unroll
                    for (int r = 0; r < 4; ++r) {
                        float v = acc[mi][ni][r] + bb;
                        if (elu) v = (v > 0.f) ? (v + 1.f) : __expf(v);
                        Cs[mi * 16 + quad * 4 + r][lcol] = f2bf(v);
                    }
            }
        }
        __syncthreads();
#pragma unroll
        for (int rd = 0; rd < 8; ++rd) {
            const int f = rd * 512 + tid;    // [0,4096): 128 rows x 32 slots
            const int row = f >> 5;
            const int sl = f & 31;
            *(uint4*)&C[(mbase + pass * 128 + row) * 512 + nbase + sl * 8] =
                *(const uint4*)&Cs[row][sl * 8];
        }
        __syncthreads();
    }
}

// out = attn @ Wo^T + bo, fp32 out.  512 blocks x 512 thr, XCD remap.
__global__ __launch_bounds__(512, 2) void out_gemm(
        const u16t* __restrict__ attn, const u16t* __restrict__ Wo,
        const u16t* __restrict__ bo, float* __restrict__ C) {
    __shared__ __align__(16) u16t sm[65536];   // 128KiB ring / Cf[64][264]
    const u32t id = blockIdx.x;
    const u32t wg = (id & 7) * 64 + (id >> 3);
    const int nbase = (int)(wg & 1u) * 256;
    const size_t mbase = (size_t)(wg >> 1) * 256;
    const int tid = threadIdx.x;
    const int w = tid >> 6, lane = tid & 63, quad = lane >> 4, l16 = lane & 15;
    const int wr = w >> 2, wc = w & 3;

    v4f acc[8][4];
    gemm256_core(attn, Wo, mbase, nbase, sm, acc, tid);
    __syncthreads();

    // fp32 tile: four 64-row passes via LDS -> float4 stores.
    float (*Cf)[264] = (float(*)[264])sm;
#pragma unroll
    for (int pass = 0; pass < 4; ++pass) {
        if (wr == (pass >> 1)) {
#pragma unroll
            for (int ni = 0; ni < 4; ++ni) {
                const int lcol = wc * 64 + ni * 16 + l16;
                const float bb = bf2f(bo[nbase + lcol]);
#pragma unroll
                for (int j = 0; j < 4; ++j) {
                    const int mi = (pass & 1) * 4 + j;
#pragma unroll
                    for (int r = 0; r < 4; ++r)
                        Cf[j * 16 + quad * 4 + r][lcol] = acc[mi][ni][r] + bb;
                }
            }
        }
        __syncthreads();
#pragma unroll
        for (int rd = 0; rd < 8; ++rd) {
            const int f = rd * 512 + tid;    // [0,4096): 64 rows x 64 f4slots
            const int row = f >> 6;
            const int sl = f & 63;
            *(float4*)&C[(mbase + pass * 64 + row) * 512 + nbase + sl * 4] =
                *(const float4*)&Cf[row][sl * 4];
        }
        __syncthreads();
    }
}

// ---------------------------------------------------------------------------
// Partial KV: Part[bh*16+chunk] = [65][64] fp32; rows 0..63 = K^T V over the
// chunk's 512 t-rows, row 64 = Ksum partial.  NO atomics.
// 1-D grid 1024 blocks, XCD-bijective remap: batch b -> XCD b, the 8
// h-blocks of one (b,chunk) adjacent in dispatch (row locality).
// ---------------------------------------------------------------------------
__global__ __launch_bounds__(256) void kv_reduce(
        const u16t* __restrict__ Kp, const u16t* __restrict__ Vp,
        float* __restrict__ Part) {
    __shared__ u16t Kl[64][66];
    __shared__ u16t Vl[64][66];
    const u32t id  = blockIdx.x;                   // [0,1024)
    const u32t swz = (id & 7) * 128 + (id >> 3);   // bijective
    const int h     = (int)(swz & 7);
    const int grp   = (int)(swz >> 3);             // b*16 + chunk
    const int b     = grp >> 4;
    const int chunk = grp & 15;
    const int bh    = b * 8 + h;
    const int tid = threadIdx.x;
    const int w = tid >> 6, lane = tid & 63, quad = lane >> 4, l16 = lane & 15;
    const int trow0 = tid >> 3;                    // 0..31
    const int c8 = (tid & 7) * 8;

    v4f acc[4];
#pragma unroll
    for (int i = 0; i < 4; ++i) acc[i] = (v4f){0.f, 0.f, 0.f, 0.f};
    float ks[8];
#pragma unroll
    for (int j = 0; j < 8; ++j) ks[j] = 0.f;

    size_t g0 = ((size_t)b * 8192 + chunk * 512 + trow0) * 512 + h * 64 + c8;
    size_t g1 = g0 + 32 * 512;
    uint4 kq0 = *(const uint4*)&Kp[g0];
    uint4 kq1 = *(const uint4*)&Kp[g1];
    uint4 vq0 = *(const uint4*)&Vp[g0];
    uint4 vq1 = *(const uint4*)&Vp[g1];

    for (int tile = 0; tile < 8; ++tile) {
        // stage current regs to LDS, fold Ksum
        *(u32t*)&Kl[trow0][c8 + 0] = kq0.x;
        *(u32t*)&Kl[trow0][c8 + 2] = kq0.y;
        *(u32t*)&Kl[trow0][c8 + 4] = kq0.z;
        *(u32t*)&Kl[trow0][c8 + 6] = kq0.w;
        *(u32t*)&Kl[trow0 + 32][c8 + 0] = kq1.x;
        *(u32t*)&Kl[trow0 + 32][c8 + 2] = kq1.y;
        *(u32t*)&Kl[trow0 + 32][c8 + 4] = kq1.z;
        *(u32t*)&Kl[trow0 + 32][c8 + 6] = kq1.w;
        *(u32t*)&Vl[trow0][c8 + 0] = vq0.x;
        *(u32t*)&Vl[trow0][c8 + 2] = vq0.y;
        *(u32t*)&Vl[trow0][c8 + 4] = vq0.z;
        *(u32t*)&Vl[trow0][c8 + 6] = vq0.w;
        *(u32t*)&Vl[trow0 + 32][c8 + 0] = vq1.x;
        *(u32t*)&Vl[trow0 + 32][c8 + 2] = vq1.y;
        *(u32t*)&Vl[trow0 + 32][c8 + 4] = vq1.z;
        *(u32t*)&Vl[trow0 + 32][c8 + 6] = vq1.w;
        {
            const v8u ku0 = __builtin_bit_cast(v8u, kq0);
            const v8u ku1 = __builtin_bit_cast(v8u, kq1);
#pragma unroll
            for (int j = 0; j < 8; ++j)
                ks[j] += bf2f(ku0[j]) + bf2f(ku1[j]);
        }
        __syncthreads();
        // issue next tile's loads now: the end-of-tile barrier's vmcnt
        // drain is then covered by the LDS-read + MFMA phase below.
        if (tile < 7) {
            g0 += 64 * 512; g1 += 64 * 512;
            kq0 = *(const uint4*)&Kp[g0];
            kq1 = *(const uint4*)&Kp[g1];
            vq0 = *(const uint4*)&Vp[g0];
            vq1 = *(const uint4*)&Vp[g1];
        }
#pragma unroll
        for (int ts = 0; ts < 2; ++ts) {
            v8u au;
#pragma unroll
            for (int j = 0; j < 8; ++j)
                au[j] = Kl[ts * 32 + quad * 8 + j][w * 16 + l16];
            const v8bf af = __builtin_bit_cast(v8bf, au);
#pragma unroll
            for (int et = 0; et < 4; ++et) {
                v8u bu;
#pragma unroll
                for (int j = 0; j < 8; ++j)
                    bu[j] = Vl[ts * 32 + quad * 8 + j][et * 16 + l16];
                acc[et] = __builtin_amdgcn_mfma_f32_16x16x32_bf16(
                    af, __builtin_bit_cast(v8bf, bu), acc[et], 0, 0, 0);
            }
        }
        __syncthreads();
    }

    // store partial KV tile (plain coalesced stores)
    const size_t pbase = (size_t)(bh * 16 + chunk) * 4160;   // 65*64
#pragma unroll
    for (int et = 0; et < 4; ++et)
#pragma unroll
        for (int r = 0; r < 4; ++r)
            Part[pbase + (size_t)(w * 16 + quad * 4 + r) * 64 + et * 16 + l16]
                = acc[et][r];

    // Ksum partial: LDS tree (reuse Kl as float [32][65], 8320B <= 8448B)
    float* kr = (float*)&Kl[0][0];
#pragma unroll
    for (int j = 0; j < 8; ++j) kr[trow0 * 65 + c8 + j] = ks[j];
    __syncthreads();
    if (tid < 64) {
        float s = 0.f;
#pragma unroll
        for (int g = 0; g < 32; ++g) s += kr[g * 65 + tid];
        Part[pbase + 4096 + tid] = s;
    }
}

// Fold 16 chunk-partials -> Ks fp32 + KVb bf16 in MFMA B-fragment order.
__global__ __launch_bounds__(256) void kv_pack(
        const float* __restrict__ Part, u16t* __restrict__ KVb,
        float* __restrict__ Ks) {
    __shared__ float kvs[64][64];
    const int bh = blockIdx.x;
    const int tid = threadIdx.x;
    const size_t base = (size_t)bh * 16 * 4160;
#pragma unroll
    for (int rr = 0; rr < 4; ++rr) {
        const int fi = rr * 256 + tid;       // 1024 float4s = 64x64
        const int d = fi >> 4;
        const int e4 = (fi & 15) * 4;
        float4 s = make_float4(0.f, 0.f, 0.f, 0.f);
        for (int c = 0; c < 16; ++c) {
            const float4 p =
                *(const float4*)&Part[base + (size_t)c * 4160 + d * 64 + e4];
            s.x += p.x; s.y += p.y; s.z += p.z; s.w += p.w;
        }
        *(float4*)&kvs[d][e4] = s;
    }
    if (tid < 64) {
        float s = 0.f;
        for (int c = 0; c < 16; ++c)
            s += Part[base + (size_t)c * 4160 + 4096 + tid];
        Ks[bh * 64 + tid] = s;
    }
    __syncthreads();
#pragma unroll
    for (int i = 0; i < 2; ++i) {
        const int c = tid + i * 256;
        const int ksi = c >> 8;
        const int nb = (c >> 6) & 3;
        const int L = c & 63;
        const int quad = L >> 4, l16 = L & 15;
        v8u pk;
#pragma unroll
        for (int j = 0; j < 8; ++j)
            pk[j] = f2bf(kvs[ksi * 32 + quad * 8 + j][nb * 16 + l16]);
        *(v8u*)&KVb[((size_t)bh * 512 + c) * 8] = pk;
    }
}

// attn = (Q @ KV) / (Q.Ksum + 1e-6), in-place over Q.  grid (512, 8).
__global__ __launch_bounds__(256) void attn_apply(
        u16t* __restrict__ Q, const u16t* __restrict__ KVb,
        const float* __restrict__ Ksum) {
    __shared__ u16t Qs[128][72];
    __shared__ float ksl[64];
    __shared__ float rden[128];
    const int bx = blockIdx.x;
    const int h = blockIdx.y;
    const int b = bx >> 6;
    const int bh = b * 8 + h;
    const int tid = threadIdx.x;
    const int w = tid >> 6, lane = tid & 63, quad = lane >> 4, l16 = lane & 15;
    const size_t row0 = (size_t)bx * 128;

#pragma unroll
    for (int i = 0; i < 4; ++i) {
        const int cid = tid + i * 256;
        const int r = cid >> 3;
        const int c8 = (cid & 7) * 8;
        *(uint4*)&Qs[r][c8] = *(const uint4*)&Q[(row0 + r) * 512 + h * 64 + c8];
    }
    if (tid < 64) ksl[tid] = Ksum[bh * 64 + tid];
    __syncthreads();

    if (tid < 128) {
        float a = 1e-6f;
#pragma unroll
        for (int d = 0; d < 64; ++d) a += bf2f(Qs[tid][d]) * ksl[d];
        rden[tid] = 1.0f / fmaxf(a, 1e-9f);
    }

    v8bf bfr[2][4];
#pragma unroll
    for (int ksi = 0; ksi < 2; ++ksi)
#pragma unroll
        for (int nb = 0; nb < 4; ++nb)
            bfr[ksi][nb] = *(const v8bf*)
                &KVb[((size_t)bh * 512 + ksi * 256 + nb * 64 + lane) * 8];
    __syncthreads();

    v4f acc[2][4];
#pragma unroll
    for (int i = 0; i < 2; ++i)
#pragma unroll
        for (int j = 0; j < 4; ++j) acc[i][j] = (v4f){0.f, 0.f, 0.f, 0.f};

#pragma unroll
    for (int ksi = 0; ksi < 2; ++ksi) {
        v8bf af[2];
#pragma unroll
        for (int mt = 0; mt < 2; ++mt)
            af[mt] = *(const v8bf*)&Qs[w * 32 + mt * 16 + l16][ksi * 32 + quad * 8];
#pragma unroll
        for (int mt = 0; mt < 2; ++mt)
#pragma unroll
            for (int nb = 0; nb < 4; ++nb)
                acc[mt][nb] = __builtin_amdgcn_mfma_f32_16x16x32_bf16(
                    af[mt], bfr[ksi][nb], acc[mt][nb], 0, 0, 0);
    }

    // restage scaled result through Qs -> coalesced uint4 stores
    __syncthreads();                     // all waves done reading Qs
#pragma unroll
    for (int mt = 0; mt < 2; ++mt)
#pragma unroll
        for (int nb = 0; nb < 4; ++nb)
#pragma unroll
            for (int r = 0; r < 4; ++r) {
                const int rl = w * 32 + mt * 16 + quad * 4 + r;
                const int e = nb * 16 + l16;
                Qs[rl][e] = f2bf(acc[mt][nb][r] * rden[rl]);
            }
    __syncthreads();
#pragma unroll
    for (int i = 0; i < 4; ++i) {
        const int f = i * 256 + tid;         // [0,1024): 128 rows x 8 slots
        const int row = f >> 3;
        const int c8 = (f & 7) * 8;
        *(uint4*)&Q[(row0 + row) * 512 + h * 64 + c8] =
            *(const uint4*)&Qs[row][c8];
    }
}

// ---------------------------------------------------------------------------
extern "C" void kernel_launch(void* const* d_in, const int* in_sizes, int n_in,
                              void* d_out, int out_size, void* d_ws, size_t ws_size,
                              hipStream_t stream) {
    (void)in_sizes; (void)n_in; (void)out_size; (void)ws_size;
    const float* x32  = (const float*)d_in[0];
    const float* Wq32 = (const float*)d_in[1];
    const float* bq32 = (const float*)d_in[2];
    const float* Wk32 = (const float*)d_in[3];
    const float* bk32 = (const float*)d_in[4];
    const float* Wv32 = (const float*)d_in[5];
    const float* bv32 = (const float*)d_in[6];
    const float* Wo32 = (const float*)d_in[7];
    const float* bo32 = (const float*)d_in[8];

    // d_out (128 MiB fp32) doubles as scratch: xb bf16 + Vb bf16.
    // After qkv_gemm, xb is dead; kv_reduce reuses its space for Part
    // (1024 x 65*64 fp32 = 17MB), read back by kv_pack before out_gemm.
    u16t* xb = (u16t*)d_out;
    u16t* Vb = (u16t*)d_out + (size_t)33554432;
    float* Part = (float*)d_out;

    char* ws = (char*)d_ws;
    const size_t SZ   = (size_t)65536 * 512 * sizeof(u16t);    // 64 MiB
    const size_t KSB  = (size_t)64 * 64 * 4;                   // 16 KiB
    const size_t KVbB = (size_t)64 * 512 * 16;                 // 512 KiB
    u16t*  Qb    = (u16t*)(ws);
    u16t*  Kb    = (u16t*)(ws + SZ);
    float* Ks    = (float*)(ws + 2 * SZ);
    u16t*  KVb   = (u16t*)(ws + 2 * SZ + KSB);
    u16t*  Wpack = (u16t*)(ws + 2 * SZ + KSB + KVbB);
    u16t*  bpack = Wpack + (size_t)4 * 262144;

    const dim3 blk(256);
    cvt_x <<<dim3(16384), blk, 0, stream>>>(x32, xb);
    cvt_wb<<<dim3(516),   blk, 0, stream>>>(Wq32, Wk32, Wv32, Wo32,
                                            bq32, bk32, bv32, bo32,
                                            Wpack, bpack);
    qkv_gemm  <<<dim3(1536), dim3(512), 0, stream>>>(xb, Wpack, bpack,
                                                     Qb, Kb, Vb);
    kv_reduce <<<dim3(1024),   blk, 0, stream>>>(Kb, Vb, Part);
    kv_pack   <<<dim3(64),     blk, 0, stream>>>(Part, KVb, Ks);
    attn_apply<<<dim3(512, 8), blk, 0, stream>>>(Qb, KVb, Ks);
    out_gemm  <<<dim3(512), dim3(512), 0, stream>>>(Qb, Wpack + 3 * 262144,
                                                    bpack + 3 * 512,
                                                    (float*)d_out);
}